// Round 2
// baseline (513.807 us; speedup 1.0000x reference)
//
#include <hip/hip_runtime.h>
#include <hip/hip_bf16.h>
#include <cstdint>

#define VOCAB 4096
#define ORDER 4
#define FAN   16388      // ORDER * (VOCAB + 1)
#define NL    2048
#define NPOS  16384      // B * L
#define NCT   129        // ceil(FAN/128) c-tiles for pipelined transpose

typedef float        f4 __attribute__((ext_vector_type(4)));
typedef unsigned int u4 __attribute__((ext_vector_type(4)));
typedef unsigned int u2 __attribute__((ext_vector_type(2)));

static __device__ __forceinline__ unsigned short f2bf(float f)
{
    __hip_bfloat16 h = __float2bfloat16(f);
    unsigned short r;
    __builtin_memcpy(&r, &h, 2);
    return r;
}

// ---------------------------------------------------------------------------
// Pass 1 (primary): persistent pipelined transpose. 256 blocks x 512 thr,
// double-buffered 2 x [128v][128c] f32 dynamic LDS (128 KB).
//   - global_load_lds width=16 (async HBM->LDS, no VGPR round trip), aux=nt
//   - LDS linear (required by global_load_lds); bank conflicts avoided by
//     pre-swizzling the per-lane GLOBAL granule: LDS granule p of row r holds
//     global granule p ^ ((r>>3)&7).  Store-phase reads are then 2-way (free).
//   - counted s_waitcnt vmcnt(4) + raw s_barrier: prefetch loads for tile t+1
//     stay in flight across the barrier while tile t is converted/stored.
//   - each block owns one 128-row v-range and sweeps c-tiles sequentially ->
//     W rows are read in ascending 512-B steps (DRAM page friendly).
// ---------------------------------------------------------------------------
__global__ __launch_bounds__(512) void k_transpose_pipe(
    const float* __restrict__ W, unsigned short* __restrict__ Wt)
{
    extern __shared__ float buf[];            // 2 * 128 * 128 floats

    const int b   = blockIdx.x;               // 256 blocks
    const int vt  = b & 31;                   // v tile 0..31
    const int g   = b >> 5;                   // c group 0..7
    const int ct0 = (g * NCT) / 8;
    const int ct1 = ((g + 1) * NCT) / 8;      // 16 or 17 tiles per block
    const int v0  = vt * 128;

    const int tid  = threadIdx.x;
    const int lane = tid & 63;
    const int w    = tid >> 6;                // wave 0..7

    // ---- load-phase constants (per lane) ----
    const int lrow_half = lane >> 5;          // 0/1: which row of the pair
    const int lgran     = lane & 31;          // LDS granule within row

    // ---- store-phase constants (per thread) ----
    const int pth = (tid & 15) * 8;           // v offset 0..120 (8 consecutive v)
    const int cb  = tid >> 4;                 // 0..31
    const int sth = (tid & 15) & 7;           // swizzle key for rows pth..pth+7

    int cur = 0;

    // stage tile ct into buf[pg]: 8 global_load_lds per wave (2 rows each)
    auto stage = [&](int ct, int pg) {
        const int c0 = ct * 128;
        #pragma unroll
        for (int i = 0; i < 8; ++i) {
            const int r = w * 16 + 2 * i + lrow_half;      // 0..127
            const int s = (r >> 3) & 7;                    // v0 multiple of 128 -> global == local key
            int c = c0 + 4 * (lgran ^ s);
            if (c + 4 > FAN) c = c0;                       // clamp: garbage, masked at store
            const float* gp = W + (size_t)(v0 + r) * FAN + c;
            float* lp = buf + pg * 16384 + (w * 16 + 2 * i) * 128;  // wave-uniform
            __builtin_amdgcn_global_load_lds(
                (const __attribute__((address_space(1))) unsigned int*)gp,
                (__attribute__((address_space(3))) unsigned int*)lp,
                16, 0, 2 /* nt */);
        }
    };

    auto store_phase = [&](int ct, int pg) {
        const int c0 = ct * 128;
        const float* bp = buf + pg * 16384;
        #pragma unroll
        for (int i = 0; i < 4; ++i) {
            const int cl = cb + 32 * i;                    // 0..127
            const int c  = c0 + cl;
            if (c < FAN) {
                const int gsw = (((cl >> 2) ^ sth) << 2) + (cl & 3);
                unsigned short sv[8];
                #pragma unroll
                for (int j = 0; j < 8; ++j)
                    sv[j] = f2bf(bp[(pth + j) * 128 + gsw]);
                u4 pk;
                pk.x = (unsigned)sv[0] | ((unsigned)sv[1] << 16);
                pk.y = (unsigned)sv[2] | ((unsigned)sv[3] << 16);
                pk.z = (unsigned)sv[4] | ((unsigned)sv[5] << 16);
                pk.w = (unsigned)sv[6] | ((unsigned)sv[7] << 16);
                *(u4*)(Wt + (size_t)c * VOCAB + v0 + pth) = pk;
            }
        }
    };

    stage(ct0, 0);
    __syncthreads();                                       // drains vmcnt(0): buf0 ready

    for (int t = ct0; t < ct1; ++t) {
        const bool more = (t + 1 < ct1);
        if (more) stage(t + 1, cur ^ 1);                   // 8 async loads in flight
        store_phase(t, cur);                               // ds_read + cvt + 4 u4 stores
        if (more) {
            // outstanding: 8 loads (older) + 4 stores (younger) -> <=4 means loads done
            asm volatile("s_waitcnt vmcnt(4)" ::: "memory");
            __builtin_amdgcn_s_barrier();
        }
        cur ^= 1;
    }
}

// ---------------------------------------------------------------------------
// Pass 1 (fallback if dynamic-LDS attribute fails): round-1 tiled transpose.
// ---------------------------------------------------------------------------
__global__ __launch_bounds__(512) void k_transpose_bf16(
    const float* __restrict__ W, unsigned short* __restrict__ Wt)
{
    __shared__ float tile[128][129];
    const int c0 = blockIdx.x * 128;
    const int v0 = blockIdx.y * 128;

    const int cq = (threadIdx.x & 31) * 4;
    const int vr = threadIdx.x >> 5;
    const bool cvalid = (c0 + cq) < FAN;

    #pragma unroll
    for (int i = 0; i < 8; ++i) {
        const int v = vr + 16 * i;
        if (cvalid) {
            const f4 f = __builtin_nontemporal_load(
                (const f4*)(W + (size_t)(v0 + v) * FAN + (c0 + cq)));
            tile[v][cq + 0] = f.x;
            tile[v][cq + 1] = f.y;
            tile[v][cq + 2] = f.z;
            tile[v][cq + 3] = f.w;
        }
    }
    __syncthreads();

    const int p  = (threadIdx.x & 15) * 8;
    const int cb = threadIdx.x >> 4;

    #pragma unroll
    for (int i = 0; i < 4; ++i) {
        const int cl = cb + 32 * i;
        const int c  = c0 + cl;
        if (c < FAN) {
            unsigned short s[8];
            #pragma unroll
            for (int j = 0; j < 8; ++j)
                s[j] = f2bf(tile[p + j][cl]);
            u4 pk;
            pk.x = (unsigned)s[0] | ((unsigned)s[1] << 16);
            pk.y = (unsigned)s[2] | ((unsigned)s[3] << 16);
            pk.z = (unsigned)s[4] | ((unsigned)s[5] << 16);
            pk.w = (unsigned)s[6] | ((unsigned)s[7] << 16);
            *(u4*)(Wt + (size_t)c * VOCAB + v0 + p) = pk;
        }
    }
}

// ---------------------------------------------------------------------------
// Pass 2: one block per FOUR consecutive positions (same batch row; NL%4==0).
//   - bias f4 loaded once per seg, reused by all 4 positions
//   - 16 independent gather streams per seg (4 tables x 4 positions)
//   - u32 byte-offsets (16 regs) instead of 16 pointer pairs
//   - stores: 4 dense 1-KB-per-wave NT float4 streams
// ---------------------------------------------------------------------------
__global__ __launch_bounds__(256) void k_gather4(
    const int* __restrict__ idx, const unsigned short* __restrict__ Wt,
    const float* __restrict__ bias, float* __restrict__ out)
{
    const int pp = blockIdx.x * 4;
    const int bb = pp >> 11;                  // / NL
    const int l0 = pp & (NL - 1);             // multiple of 4
    const int* row = idx + bb * NL;

    unsigned off[4][ORDER];                   // byte offsets into Wt (<=134 MB)
    #pragma unroll
    for (int p = 0; p < 4; ++p) {
        #pragma unroll
        for (int k = 0; k < ORDER; ++k) {
            const int s   = ORDER - 1 - k;
            const int lp  = l0 + p;
            const int tok = (lp >= s) ? row[lp - s] : VOCAB;  // pad token
            off[p][k] = (unsigned)(((size_t)(k * (VOCAB + 1) + tok) * VOCAB) * 2u);
        }
    }

    const char* Wb = (const char*)Wt;
    float* o = out + (size_t)pp * VOCAB;
    const int j4 = threadIdx.x * 4;           // 4 consecutive v per thread

    #pragma unroll
    for (int seg = 0; seg < 4; ++seg) {
        const int v    = seg * 1024 + j4;
        const int voff = v * 2;

        const f4 bv = *(const f4*)(bias + v);

        u2 wv[4][ORDER];
        #pragma unroll
        for (int p = 0; p < 4; ++p)
            #pragma unroll
            for (int k = 0; k < ORDER; ++k)
                wv[p][k] = *(const u2*)(Wb + off[p][k] + voff);

        #pragma unroll
        for (int p = 0; p < 4; ++p) {
            float a0 = bv.x, a1 = bv.y, a2 = bv.z, a3 = bv.w;
            #pragma unroll
            for (int k = 0; k < ORDER; ++k) {
                const unsigned lo = wv[p][k].x, hi = wv[p][k].y;
                a0 += __uint_as_float(lo << 16);
                a1 += __uint_as_float(lo & 0xFFFF0000u);
                a2 += __uint_as_float(hi << 16);
                a3 += __uint_as_float(hi & 0xFFFF0000u);
            }
            f4 sv; sv.x = a0; sv.y = a1; sv.z = a2; sv.w = a3;
            __builtin_nontemporal_store(sv, (f4*)(o + (size_t)p * VOCAB + v));
        }
    }
}

// ---------------------------------------------------------------------------
// Fallback (ws too small): direct strided reads from W.  Correct, slower.
// ---------------------------------------------------------------------------
__global__ __launch_bounds__(256) void k_direct(
    const int* __restrict__ idx, const float* __restrict__ W,
    const float* __restrict__ bias, float* __restrict__ out)
{
    const int pos = blockIdx.x;
    const int bb  = pos >> 11;
    const int ll  = pos & (NL - 1);
    const int* row = idx + bb * NL;

    int off[ORDER];
    #pragma unroll
    for (int k = 0; k < ORDER; ++k) {
        const int s   = ORDER - 1 - k;
        const int tok = (ll >= s) ? row[ll - s] : VOCAB;
        off[k] = k * (VOCAB + 1) + tok;
    }

    float* o = out + (size_t)pos * VOCAB;
    for (int v = threadIdx.x; v < VOCAB; v += 256) {
        const float* wr = W + (size_t)v * FAN;
        o[v] = bias[v] + wr[off[0]] + wr[off[1]] + wr[off[2]] + wr[off[3]];
    }
}

// ---------------------------------------------------------------------------
extern "C" void kernel_launch(void* const* d_in, const int* in_sizes, int n_in,
                              void* d_out, int out_size, void* d_ws, size_t ws_size,
                              hipStream_t stream)
{
    const int*   idx  = (const int*)d_in[0];
    const float* W    = (const float*)d_in[1];
    const float* bias = (const float*)d_in[2];
    float*       out  = (float*)d_out;

    const size_t wt_bytes = (size_t)FAN * VOCAB * 2;   // 134.25 MB

    if (ws_size >= wt_bytes) {
        unsigned short* Wt = (unsigned short*)d_ws;

        static int pipe_ok = -1;
        if (pipe_ok < 0) {
            pipe_ok = (hipFuncSetAttribute(
                           (const void*)k_transpose_pipe,
                           hipFuncAttributeMaxDynamicSharedMemorySize,
                           131072) == hipSuccess) ? 1 : 0;
        }

        if (pipe_ok) {
            k_transpose_pipe<<<256, 512, 131072, stream>>>(W, Wt);
        } else {
            dim3 g1((FAN + 127) / 128, VOCAB / 128);
            k_transpose_bf16<<<g1, 512, 0, stream>>>(W, Wt);
        }
        k_gather4<<<NPOS / 4, 256, 0, stream>>>(idx, Wt, bias, out);
    } else {
        k_direct<<<NPOS, 256, 0, stream>>>(idx, W, bias, out);
    }
}